// Round 1
// baseline (24.358 us; speedup 1.0000x reference)
//
#include <hip/hip_runtime.h>

// SWT-Haar level-1 MSE loss.
// Identity: mean((swt(x)-swt(t))^2 over stacked [cA,cD]) == mean((x-t)^2).
// Proof: with d = x-t, dr = roll(d,-1):
//   (cA_x-cA_t)^2 + (cD_x-cD_t)^2 = 0.5[(d+dr)^2 + (dr-d)^2] = d^2 + dr^2,
//   and sum(dr^2) == sum(d^2) (circular shift is a permutation per row),
//   so sum over 2N coeffs = 2*sum(d^2)  =>  mean = sum(d^2)/N = MSE.
// => memory-bound reduction over 2 x 50.3 MB of f32.

#define NBLOCKS 2048   // 8 blocks/CU on 256 CUs
#define NTHREADS 256

__global__ __launch_bounds__(NTHREADS)
void swt_mse_partial(const float4* __restrict__ x,
                     const float4* __restrict__ t,
                     double* __restrict__ part, int n4) {
    int tid = blockIdx.x * blockDim.x + threadIdx.x;
    int stride = gridDim.x * blockDim.x;

    float acc = 0.0f;  // <=24 terms/thread: f32 accumulation error negligible
    for (int i = tid; i < n4; i += stride) {
        float4 a = x[i];
        float4 b = t[i];
        float d0 = a.x - b.x;
        float d1 = a.y - b.y;
        float d2 = a.z - b.z;
        float d3 = a.w - b.w;
        acc += d0 * d0 + d1 * d1 + d2 * d2 + d3 * d3;
    }

    double dacc = (double)acc;
    // wave64 butterfly reduce
    for (int off = 32; off > 0; off >>= 1)
        dacc += __shfl_down(dacc, off, 64);

    __shared__ double sm[NTHREADS / 64];
    int lane = threadIdx.x & 63;
    int wid  = threadIdx.x >> 6;
    if (lane == 0) sm[wid] = dacc;
    __syncthreads();
    if (threadIdx.x == 0) {
        double s = 0.0;
        #pragma unroll
        for (int w = 0; w < NTHREADS / 64; ++w) s += sm[w];
        part[blockIdx.x] = s;  // every slot written every call -> deterministic
    }
}

__global__ __launch_bounds__(256)
void swt_mse_final(const double* __restrict__ part, float* __restrict__ out,
                   int nparts, double invN) {
    double acc = 0.0;
    for (int i = threadIdx.x; i < nparts; i += 256) acc += part[i];
    for (int off = 32; off > 0; off >>= 1)
        acc += __shfl_down(acc, off, 64);

    __shared__ double sm[4];
    int lane = threadIdx.x & 63;
    int wid  = threadIdx.x >> 6;
    if (lane == 0) sm[wid] = acc;
    __syncthreads();
    if (threadIdx.x == 0) {
        double s = sm[0] + sm[1] + sm[2] + sm[3];
        out[0] = (float)(s * invN);
    }
}

extern "C" void kernel_launch(void* const* d_in, const int* in_sizes, int n_in,
                              void* d_out, int out_size, void* d_ws, size_t ws_size,
                              hipStream_t stream) {
    const float* x = (const float*)d_in[0];
    const float* t = (const float*)d_in[1];
    float* out = (float*)d_out;
    double* part = (double*)d_ws;  // NBLOCKS * 8 B = 16 KB scratch

    long long N = (long long)in_sizes[0];   // 16*3*512*512 = 12,582,912
    int n4 = (int)(N / 4);                  // divisible by 4

    swt_mse_partial<<<NBLOCKS, NTHREADS, 0, stream>>>(
        (const float4*)x, (const float4*)t, part, n4);
    swt_mse_final<<<1, 256, 0, stream>>>(part, out, NBLOCKS, 1.0 / (double)N);
}